// Round 2
// baseline (1592.200 us; speedup 1.0000x reference)
//
#include <hip/hip_runtime.h>
#include <stdint.h>

// Grouped GEMM: Y_e = X_e @ W_e^T, E=64 experts, 256 tokens each, K=N=2048.
// fp32 inputs/outputs; compute in bf16 MFMA (threshold permits bf16 error).
// Memory-bound: min traffic = W(1GiB fp32) + X(128MiB) + Y(128MiB) ~ 204us @ 6.3TB/s.

#define NEXP 64
#define KDIM 2048
#define NDIM 2048
#define BM 128
#define BN 128
#define BK 32
#define KTILES (KDIM / BK)   // 64
#define LDAS 40              // LDS row stride in bf16 elems (80B = 20 banks, pad)

typedef __attribute__((ext_vector_type(8))) short bf16x8;
typedef __attribute__((ext_vector_type(4))) float f32x4;

__device__ __forceinline__ uint32_t pack2_bf16_rtne(float x, float y) {
  uint32_t ux = __float_as_uint(x), uy = __float_as_uint(y);
  ux += 0x7FFFu + ((ux >> 16) & 1u);   // round-to-nearest-even
  uy += 0x7FFFu + ((uy >> 16) & 1u);
  return (ux >> 16) | (uy & 0xFFFF0000u);
}

__global__ __launch_bounds__(256)
void grouped_gemm_bf16(const float* __restrict__ X,
                       const float* __restrict__ W,
                       const int* __restrict__ m_offsets,
                       float* __restrict__ Y) {
  __shared__ unsigned short As[BM][LDAS];
  __shared__ unsigned short Bs[BN][LDAS];

  // block mapping: m-tile fastest so the 2 M-tiles sharing a W slice are
  // dispatched adjacently (L2/L3 reuse of the 1MiB W tile).
  const int bx = blockIdx.x;
  const int e  = bx >> 5;          // 32 blocks per expert
  const int t  = bx & 31;
  const int mt = t & 1;            // 2 M-tiles (256 rows / 128)
  const int nt = t >> 1;           // 16 N-tiles

  const int tid  = threadIdx.x;
  const int lane = tid & 63;
  const int wave = tid >> 6;
  const int wm   = wave & 1;       // wave's 64x64 quadrant
  const int wn   = wave >> 1;
  const int fr   = lane & 15;      // fragment row (m or n index)
  const int q    = lane >> 4;      // k-quad (0..3), 8 bf16 each

  const int row_base = m_offsets[e];

  // staging: 256 threads cover a 128x32 fp32 tile in 4 passes of 32 rows;
  // 8 threads per row, float4 (16B) each.
  const int lr = tid >> 3;         // 0..31
  const int ks = (tid & 7) * 4;    // float offset within BK

  const float* Aptr = X + (size_t)(row_base + mt * BM + lr) * KDIM + ks;
  const float* Bptr = W + ((size_t)e * NDIM + (size_t)(nt * BN + lr)) * KDIM + ks;

  float4 ar[4], br[4];
#pragma unroll
  for (int p = 0; p < 4; ++p) {
    ar[p] = *(const float4*)(Aptr + (size_t)p * 32 * KDIM);
    br[p] = *(const float4*)(Bptr + (size_t)p * 32 * KDIM);
  }

  f32x4 acc[4][4];
#pragma unroll
  for (int i = 0; i < 4; ++i)
#pragma unroll
    for (int j = 0; j < 4; ++j) {
      f32x4 z = {0.f, 0.f, 0.f, 0.f};
      acc[i][j] = z;
    }

  for (int kt = 0; kt < KTILES; ++kt) {
    // convert staged fp32 regs -> bf16 -> LDS
#pragma unroll
    for (int p = 0; p < 4; ++p) {
      uint2 pa, pb;
      pa.x = pack2_bf16_rtne(ar[p].x, ar[p].y);
      pa.y = pack2_bf16_rtne(ar[p].z, ar[p].w);
      pb.x = pack2_bf16_rtne(br[p].x, br[p].y);
      pb.y = pack2_bf16_rtne(br[p].z, br[p].w);
      *(uint2*)&As[lr + 32 * p][ks] = pa;
      *(uint2*)&Bs[lr + 32 * p][ks] = pb;
    }
    __syncthreads();

    // issue next tile's global loads early; vmcnt wait lands at next
    // iteration's convert, hidden under this iteration's MFMAs.
    if (kt + 1 < KTILES) {
      const float* a2 = Aptr + (size_t)(kt + 1) * BK;
      const float* b2 = Bptr + (size_t)(kt + 1) * BK;
#pragma unroll
      for (int p = 0; p < 4; ++p) {
        ar[p] = *(const float4*)(a2 + (size_t)p * 32 * KDIM);
        br[p] = *(const float4*)(b2 + (size_t)p * 32 * KDIM);
      }
    }

    // LDS -> fragments -> MFMA
    bf16x8 af[4], bg[4];
#pragma unroll
    for (int i = 0; i < 4; ++i) {
      af[i] = *(const bf16x8*)&As[wm * 64 + i * 16 + fr][q * 8];
      bg[i] = *(const bf16x8*)&Bs[wn * 64 + i * 16 + fr][q * 8];
    }
#pragma unroll
    for (int i = 0; i < 4; ++i)
#pragma unroll
      for (int j = 0; j < 4; ++j)
        acc[i][j] = __builtin_amdgcn_mfma_f32_16x16x32_bf16(af[i], bg[j], acc[i][j], 0, 0, 0);

    __syncthreads();
  }

  // epilogue: C/D layout col=lane&15, row=(lane>>4)*4+reg  [m89-verified]
  const int gm0 = row_base + mt * BM + wm * 64;
  const int gn0 = nt * BN + wn * 64;
#pragma unroll
  for (int i = 0; i < 4; ++i) {
    const int r0 = gm0 + i * 16 + q * 4;
#pragma unroll
    for (int j = 0; j < 4; ++j) {
      const int c = gn0 + j * 16 + fr;
#pragma unroll
      for (int r = 0; r < 4; ++r)
        Y[(size_t)(r0 + r) * NDIM + c] = acc[i][j][r];
    }
  }
}

extern "C" void kernel_launch(void* const* d_in, const int* in_sizes, int n_in,
                              void* d_out, int out_size, void* d_ws, size_t ws_size,
                              hipStream_t stream) {
  const float* X = (const float*)d_in[0];        // [16384, 2048]
  const float* W = (const float*)d_in[1];        // [64, 2048, 2048]
  const int* m_offsets = (const int*)d_in[3];    // [65]
  float* Y = (float*)d_out;                      // [16384, 2048]

  dim3 grid(NEXP * (256 / BM) * (NDIM / BN));    // 64 * 2 * 16 = 2048
  dim3 block(256);
  grouped_gemm_bf16<<<grid, block, 0, stream>>>(X, W, m_offsets, Y);
}